// Round 7
// baseline (134.997 us; speedup 1.0000x reference)
//
#include <hip/hip_runtime.h>

#define N 8192
#define D 128
// (1/0.07) * log2(e): fold temperature AND base-2 conversion into A-side scale
#define SCALE_A 20.6098592f
#define NP 64             // 8192 / 128-row panels
#define NBLK 512          // 64 panels x 8 m-chunks
#define NBLK_PREP 256

using short8  = __attribute__((ext_vector_type(8))) short;
using float4v = __attribute__((ext_vector_type(4))) float;

#if __has_builtin(__builtin_amdgcn_exp2f)
#define EXP2(x) __builtin_amdgcn_exp2f(x)
#else
#define EXP2(x) __expf((x) * 0.69314718f)
#endif

// float -> bf16 (RNE) as raw ushort
static __device__ inline unsigned int f2bf(float f) {
    union { float f; unsigned int u; } x;
    x.f = f;
    unsigned int u = x.u;
    return (u + 0x7FFFu + ((u >> 16) & 1u)) >> 16;
}

// Pre-pass: emb fp32 -> bf16 (unscaled, B-side) and bf16*SCALE_A (A-side).
// Also zeroes tot/pos and the ticket. 65536 threads x 16 elements.
__global__ __launch_bounds__(256) void cl_prep(
    const float* __restrict__ emb, unsigned short* __restrict__ bfB,
    unsigned short* __restrict__ bfA, float* __restrict__ tot,
    int* __restrict__ ticket)
{
    const int t = blockIdx.x * 256 + threadIdx.x;
    const float* p = emb + (size_t)t * 16;
    uint4 ob[2], oa[2];
    #pragma unroll
    for (int h = 0; h < 2; ++h) {
        float4v f0 = *(const float4v*)(p + h * 8);
        float4v f1 = *(const float4v*)(p + h * 8 + 4);
        ob[h].x = f2bf(f0[0]) | (f2bf(f0[1]) << 16);
        ob[h].y = f2bf(f0[2]) | (f2bf(f0[3]) << 16);
        ob[h].z = f2bf(f1[0]) | (f2bf(f1[1]) << 16);
        ob[h].w = f2bf(f1[2]) | (f2bf(f1[3]) << 16);
        oa[h].x = f2bf(f0[0] * SCALE_A) | (f2bf(f0[1] * SCALE_A) << 16);
        oa[h].y = f2bf(f0[2] * SCALE_A) | (f2bf(f0[3] * SCALE_A) << 16);
        oa[h].z = f2bf(f1[0] * SCALE_A) | (f2bf(f1[1] * SCALE_A) << 16);
        oa[h].w = f2bf(f1[2] * SCALE_A) | (f2bf(f1[3] * SCALE_A) << 16);
    }
    ((uint4*)bfB)[t * 2]     = ob[0];
    ((uint4*)bfB)[t * 2 + 1] = ob[1];
    ((uint4*)bfA)[t * 2]     = oa[0];
    ((uint4*)bfA)[t * 2 + 1] = oa[1];
    if (t < 2 * N) tot[t] = 0.f;    // tot and pos are contiguous
    if (t == 0) *ticket = 0;
}

// Symmetric main kernel, STREAMING variant. Six rounds showed cl_main's time
// is invariant to work content (41/45/~40 us at full/full/half FLOPs): the
// binding constraint is the per-tile stage->drain->barrier structure, not
// any pipe (all <35% busy). bfB is 2 MB = L2-resident on every XCD, so this
// version deletes LDS staging and ALL intra-block synchronization: each wave
// reads B fragments directly from L2 inside the MFMA loop (32 independent
// dwordx4 loads/tile, 64B-aligned fully-used segments; ks = 64B immediate
// offset off one per-tc base). Waves are fully independent -> compiler
// pipelines loads vs MFMA with counted vmcnt (its strong regime). L2 floor:
// 2080 tiles x 8 waves x 32KB = 532 MB / 34.5 TB/s ~= 15 us.
// Coverage mapping unchanged from R6 (verified bit-exact): block (i,cid)
// owns j=(i+m)&63 for m in {4cid..4cid+3}; m=32 only for i<32 (on cid 0).
// (512,2): 256-VGPR cap (b-frag pipelining needs ~180; R3 taught never to
// squeeze into 128), 8 waves/CU, latency hidden by per-wave MLP.
__global__ __launch_bounds__(512, 2) void cl_main(
    const unsigned short* __restrict__ bfA, const unsigned short* __restrict__ bfB,
    const int* __restrict__ labels,
    float* __restrict__ tot, float* __restrict__ pos,
    int* __restrict__ ticket, float* __restrict__ out)
{
    __shared__ float sred[2][8];
    __shared__ int   s_ticket;

    const int tid  = threadIdx.x;
    const int lane = tid & 63;
    const int wave = tid >> 6;    // 0..7 = this wave's 16-row strip
    const int q    = lane >> 4;   // quad id 0..3
    const int c    = lane & 15;

    const int i   = blockIdx.x >> 3;   // row panel 0..63
    const int cid = blockIdx.x & 7;    // m-chunk
    const int nit = (cid == 0 && i < 32) ? 5 : 4;
    const int R0r = i * 128;

    // ---- A fragments + row labels, once per block ----
    short8 afrag[4];
    int rowlab[4];
    {
        const int arow = R0r + wave * 16 + c;
        #pragma unroll
        for (int ks = 0; ks < 4; ++ks)
            afrag[ks] = *(const short8*)(bfA + (size_t)arow * D + ks * 32 + q * 8);
        #pragma unroll
        for (int reg = 0; reg < 4; ++reg)
            rowlab[reg] = labels[R0r + wave * 16 + q * 4 + reg];
    }

    float tot_a[4] = {0.f, 0.f, 0.f, 0.f};   // row partials, panel i (persist)
    float pos_a[4] = {0.f, 0.f, 0.f, 0.f};

    #pragma unroll 1
    for (int it = 0; it < nit; ++it) {
        const int m    = (cid == 0) ? ((it == 4) ? 32 : it) : (cid * 4 + it);
        const int j    = (i + m) & 63;
        const int C0   = j * 128;
        const bool diag = (m == 0);

        int collab[8];
        #pragma unroll
        for (int tc = 0; tc < 8; ++tc)
            collab[tc] = labels[C0 + tc * 16 + c];

        // ---- MFMA: B fragments streamed straight from L2, no LDS/barriers ----
        float4v acc[8];
        #pragma unroll
        for (int tc = 0; tc < 8; ++tc) {
            float4v z = {0.f, 0.f, 0.f, 0.f};
            acc[tc] = z;
        }
        #pragma unroll
        for (int tc = 0; tc < 8; ++tc) {
            if (diag && tc < wave) continue;       // wave-uniform skip
            // per-lane base: row C0+tc*16+c, col q*8; ks = +64B immediates
            const short8* bp = (const short8*)(bfB + (size_t)(C0 + tc * 16 + c) * D + q * 8);
            #pragma unroll
            for (int ks = 0; ks < 4; ++ks) {
                short8 b = bp[ks * 4];             // ks*32 shorts = 64B offset
                acc[tc] = __builtin_amdgcn_mfma_f32_16x16x32_bf16(
                    afrag[ks], b, acc[tc], 0, 0, 0);
            }
        }

        // ---- epilogue: exp2 once, accumulate rows AND mirrored columns ----
        float ctot[8] = {0,0,0,0,0,0,0,0};
        float cpos[8] = {0,0,0,0,0,0,0,0};
        #pragma unroll
        for (int tc = 0; tc < 8; ++tc) {
            if (diag && tc < wave) continue;           // covered by mirror tile
            const int lc = collab[tc];
            if (diag && tc == wave) {
                // diagonal 16x16: keep strictly-upper r<c; r==c excluded,
                // r>c is this tile's own mirror.
                #pragma unroll
                for (int reg = 0; reg < 4; ++reg) {
                    float v = EXP2(acc[tc][reg]);
                    if ((q * 4 + reg) >= c) v = 0.f;
                    tot_a[reg] += v;  ctot[tc] += v;
                    if (rowlab[reg] == lc) { pos_a[reg] += v; cpos[tc] += v; }
                }
            } else {
                #pragma unroll
                for (int reg = 0; reg < 4; ++reg) {
                    float v = EXP2(acc[tc][reg]);
                    tot_a[reg] += v;  ctot[tc] += v;
                    if (rowlab[reg] == lc) { pos_a[reg] += v; cpos[tc] += v; }
                }
            }
        }

        // ---- flush column partials for panel j: 2x shfl + coalesced atomics
        #pragma unroll
        for (int tc = 0; tc < 8; ++tc) {
            if (diag && tc < wave) continue;           // zero partials
            float t = ctot[tc], p = cpos[tc];
            t += __shfl_xor(t, 16, 64);  t += __shfl_xor(t, 32, 64);
            p += __shfl_xor(p, 16, 64);  p += __shfl_xor(p, 32, 64);
            if (q == 0) {
                const int cc = C0 + tc * 16 + c;       // lanes 0..15 coalesced
                atomicAdd(&tot[cc], t);
                atomicAdd(&pos[cc], p);
            }
        }
    }

    // ---- row reduction over the 16 column-lanes, one atomic per row ----
    #pragma unroll
    for (int reg = 0; reg < 4; ++reg) {
        float t = tot_a[reg];
        float p = pos_a[reg];
        #pragma unroll
        for (int m = 1; m < 16; m <<= 1) {
            t += __shfl_xor(t, m, 64);
            p += __shfl_xor(p, m, 64);
        }
        if (c == 0) {
            const int r = R0r + wave * 16 + q * 4 + reg;
            atomicAdd(&tot[r], t);   // device-scope RMW at coherent point
            atomicAdd(&pos[r], p);
        }
    }

    // ---- last-block finalize: completion-wait + relaxed ticket (NO cache ops)
    asm volatile("s_waitcnt vmcnt(0)" ::: "memory");  // our atomics committed
    __syncthreads();
    if (tid == 0)
        s_ticket = __hip_atomic_fetch_add(ticket, 1, __ATOMIC_RELAXED,
                                          __HIP_MEMORY_SCOPE_AGENT);
    __syncthreads();
    if (s_ticket != NBLK - 1) return;

    float lsum = 0.f, lcnt = 0.f;
    #pragma unroll 4
    for (int idx = tid; idx < N; idx += 512) {
        const float t = __hip_atomic_load(&tot[idx], __ATOMIC_RELAXED,
                                          __HIP_MEMORY_SCOPE_AGENT);
        const float p = __hip_atomic_load(&pos[idx], __ATOMIC_RELAXED,
                                          __HIP_MEMORY_SCOPE_AGENT);
        const float loss = -__logf(p / (t + 1e-8f) + 1e-8f);
        if (p > 0.f) { lsum += loss; lcnt += 1.f; }   // valid <=> pos>0
    }
    #pragma unroll
    for (int m = 1; m < 64; m <<= 1) {
        lsum += __shfl_xor(lsum, m, 64);
        lcnt += __shfl_xor(lcnt, m, 64);
    }
    if (lane == 0) { sred[0][wave] = lsum; sred[1][wave] = lcnt; }
    __syncthreads();
    if (tid == 0) {
        float s = 0.f, n = 0.f;
        #pragma unroll
        for (int w = 0; w < 8; ++w) { s += sred[0][w]; n += sred[1][w]; }
        out[0] = (n > 0.f) ? s / fmaxf(n, 1.f) : 0.f;
    }
}

extern "C" void kernel_launch(void* const* d_in, const int* in_sizes, int n_in,
                              void* d_out, int out_size, void* d_ws, size_t ws_size,
                              hipStream_t stream) {
    const float* emb  = (const float*)d_in[0];
    const int* labels = (const int*)d_in[1];
    unsigned short* bfB = (unsigned short*)d_ws;                       // 2 MB
    unsigned short* bfA = bfB + (size_t)N * D;                         // 2 MB
    float* tot    = (float*)(bfA + (size_t)N * D);
    float* pos    = tot + N;
    int*   ticket = (int*)(pos + N);

    cl_prep<<<NBLK_PREP, 256, 0, stream>>>(emb, bfB, bfA, tot, ticket);
    cl_main<<<NBLK, 512, 0, stream>>>(bfA, bfB, labels, tot, pos,
                                      ticket, (float*)d_out);
}

// Round 8
// 98.409 us; speedup vs baseline: 1.3718x; 1.3718x over previous
//
#include <hip/hip_runtime.h>

#define N 8192
#define D 128
// (1/0.07) * log2(e): fold temperature AND base-2 conversion into A-side scale
#define SCALE_A 20.6098592f
#define NBLK 1024         // 64 row-blocks x 16 col-strips
#define NBLK_PREP 256

using short8  = __attribute__((ext_vector_type(8))) short;
using float4v = __attribute__((ext_vector_type(4))) float;

#if __has_builtin(__builtin_amdgcn_exp2f)
#define EXP2(x) __builtin_amdgcn_exp2f(x)
#else
#define EXP2(x) __expf((x) * 0.69314718f)
#endif

// float -> bf16 (RNE) as raw ushort
static __device__ inline unsigned int f2bf(float f) {
    union { float f; unsigned int u; } x;
    x.f = f;
    unsigned int u = x.u;
    return (u + 0x7FFFu + ((u >> 16) & 1u)) >> 16;
}

// Pre-pass: emb fp32 -> FRAGMENT-MAJOR bf16 operands. Slot layout (short8
// units): idx = (tile16*4 + ks)*64 + q*16 + c holds elements
// emb[tile16*16 + c][ks*32 + q*8 .. +8]  (A side additionally * SCALE_A).
// This is exactly the per-lane fragment the proven kernels fed to
// mfma_16x16x32_bf16 — same lane->element mapping, now contiguous in lane
// order so a wave's fragment load is ONE 1KB coalesced segment.
// Thread t: row r = t>>3, 16-elem chunk s = t&7 -> (ks = s>>1, q0 = (s&1)*2),
// writes 2 short8 slots per operand. Also zeroes tot/pos and the ticket.
__global__ __launch_bounds__(256) void cl_prep(
    const float* __restrict__ emb, unsigned short* __restrict__ bfA,
    unsigned short* __restrict__ bfB, float* __restrict__ tot,
    int* __restrict__ ticket)
{
    const int t  = blockIdx.x * 256 + threadIdx.x;
    const int r  = t >> 3;
    const int s  = t & 7;
    const int ks = s >> 1;
    const int h  = s & 1;          // q0 = 2h
    const int rt = r >> 4;
    const int c  = r & 15;
    const int base = (rt * 4 + ks) * 64 + h * 32 + c;   // short8 index, q0 slot

    const float* p = emb + (size_t)r * D + s * 16;
    float4v f0 = *(const float4v*)(p);
    float4v f1 = *(const float4v*)(p + 4);
    float4v f2 = *(const float4v*)(p + 8);
    float4v f3 = *(const float4v*)(p + 12);

    uint4 b0, b1, a0, a1;
    b0.x = f2bf(f0[0]) | (f2bf(f0[1]) << 16);
    b0.y = f2bf(f0[2]) | (f2bf(f0[3]) << 16);
    b0.z = f2bf(f1[0]) | (f2bf(f1[1]) << 16);
    b0.w = f2bf(f1[2]) | (f2bf(f1[3]) << 16);
    b1.x = f2bf(f2[0]) | (f2bf(f2[1]) << 16);
    b1.y = f2bf(f2[2]) | (f2bf(f2[3]) << 16);
    b1.z = f2bf(f3[0]) | (f2bf(f3[1]) << 16);
    b1.w = f2bf(f3[2]) | (f2bf(f3[3]) << 16);
    a0.x = f2bf(f0[0] * SCALE_A) | (f2bf(f0[1] * SCALE_A) << 16);
    a0.y = f2bf(f0[2] * SCALE_A) | (f2bf(f0[3] * SCALE_A) << 16);
    a0.z = f2bf(f1[0] * SCALE_A) | (f2bf(f1[1] * SCALE_A) << 16);
    a0.w = f2bf(f1[2] * SCALE_A) | (f2bf(f1[3] * SCALE_A) << 16);
    a1.x = f2bf(f2[0] * SCALE_A) | (f2bf(f2[1] * SCALE_A) << 16);
    a1.y = f2bf(f2[2] * SCALE_A) | (f2bf(f2[3] * SCALE_A) << 16);
    a1.z = f2bf(f3[0] * SCALE_A) | (f2bf(f3[1] * SCALE_A) << 16);
    a1.w = f2bf(f3[2] * SCALE_A) | (f2bf(f3[3] * SCALE_A) << 16);

    ((uint4*)bfA)[base]      = a0;   // q0
    ((uint4*)bfA)[base + 16] = a1;   // q0+1
    ((uint4*)bfB)[base]      = b0;
    ((uint4*)bfB)[base + 16] = b1;

    if (t < 2 * N) tot[t] = 0.f;    // tot and pos are contiguous
    if (t == 0) *ticket = 0;
}

// Barrier-free streaming main kernel. R7 proved streaming dies on scattered
// loads (256B lane stride -> 16 segments/load, 85us); this version's
// fragment-major layout makes EVERY in-loop load one 1KB coalesced segment.
// No LDS, no barriers, no waitcnt drains in the loop: each wave owns an
// independent 32-row x 512-col stream (2 row-tiles x 32 col-tiles; per
// col-tile: 4 B-frag loads + 1 label load + 8 MFMA + ~40 VALU epilogue).
// 4 waves/block walk the same col-strip -> B loads hit L1 (~4x traffic cut).
// Grid 1024 = 64 row-blocks x 16 col-strips, (256,4): ~110 regs (margin
// under the 128 cap — R3's spill was 190-into-128), 16 waves/CU.
// Reduction/finalize = proven ticket + atomicAdd path.
__global__ __launch_bounds__(256, 4) void cl_main(
    const unsigned short* __restrict__ bfA, const unsigned short* __restrict__ bfB,
    const int* __restrict__ labels,
    float* __restrict__ tot, float* __restrict__ pos,
    int* __restrict__ ticket, float* __restrict__ out)
{
    __shared__ float sred[2][4];
    __shared__ int   s_ticket;

    const int tid  = threadIdx.x;
    const int lane = tid & 63;
    const int wave = tid >> 6;
    const int q    = lane >> 4;   // quad id 0..3
    const int c    = lane & 15;

    const int rb = blockIdx.x & 63;        // row block: 128 rows
    const int cs = blockIdx.x >> 6;        // col strip: 512 cols
    const int w0  = rb * 128 + wave * 32;  // this wave's first row
    const int rt0 = w0 >> 4;               // first of 2 row-tile indices
    const int ct0 = cs * 32;               // first of 32 col-tile indices

    const short8* A8 = (const short8*)bfA;
    const short8* B8 = (const short8*)bfB;

    // ---- A fragments (coalesced 1KB loads) + row labels, once per wave ----
    short8 afrag[2][4];
    int rowlab[2][4];
    #pragma unroll
    for (int tr = 0; tr < 2; ++tr) {
        #pragma unroll
        for (int ks = 0; ks < 4; ++ks)
            afrag[tr][ks] = A8[((rt0 + tr) * 4 + ks) * 64 + lane];
        #pragma unroll
        for (int reg = 0; reg < 4; ++reg)
            rowlab[tr][reg] = labels[w0 + tr * 16 + q * 4 + reg];
    }

    float tot_a[2][4] = {{0.f,0.f,0.f,0.f},{0.f,0.f,0.f,0.f}};
    float pos_a[2][4] = {{0.f,0.f,0.f,0.f},{0.f,0.f,0.f,0.f}};

    #pragma unroll 2
    for (int t = 0; t < 32; ++t) {
        const int ct = ct0 + t;
        const short8* bp = B8 + (size_t)ct * 256;   // 4 x 1KB fragments
        short8 b0 = bp[lane];
        short8 b1 = bp[64 + lane];
        short8 b2 = bp[128 + lane];
        short8 b3 = bp[192 + lane];
        const int lc = labels[ct * 16 + c];         // one 64B segment

        float4v acc0 = {0.f, 0.f, 0.f, 0.f};
        float4v acc1 = {0.f, 0.f, 0.f, 0.f};
        acc0 = __builtin_amdgcn_mfma_f32_16x16x32_bf16(afrag[0][0], b0, acc0, 0, 0, 0);
        acc1 = __builtin_amdgcn_mfma_f32_16x16x32_bf16(afrag[1][0], b0, acc1, 0, 0, 0);
        acc0 = __builtin_amdgcn_mfma_f32_16x16x32_bf16(afrag[0][1], b1, acc0, 0, 0, 0);
        acc1 = __builtin_amdgcn_mfma_f32_16x16x32_bf16(afrag[1][1], b1, acc1, 0, 0, 0);
        acc0 = __builtin_amdgcn_mfma_f32_16x16x32_bf16(afrag[0][2], b2, acc0, 0, 0, 0);
        acc1 = __builtin_amdgcn_mfma_f32_16x16x32_bf16(afrag[1][2], b2, acc1, 0, 0, 0);
        acc0 = __builtin_amdgcn_mfma_f32_16x16x32_bf16(afrag[0][3], b3, acc0, 0, 0, 0);
        acc1 = __builtin_amdgcn_mfma_f32_16x16x32_bf16(afrag[1][3], b3, acc1, 0, 0, 0);

        // ---- epilogue: exp2, diagonal/label masking, per-row accumulate ----
        if (ct == rt0) {                      // wave-uniform: diag tile, tr=0
            #pragma unroll
            for (int reg = 0; reg < 4; ++reg) {
                float v = EXP2(acc0[reg]);
                if ((q * 4 + reg) == c) v = 0.f;
                tot_a[0][reg] += v;
                if (rowlab[0][reg] == lc) pos_a[0][reg] += v;
            }
        } else {
            #pragma unroll
            for (int reg = 0; reg < 4; ++reg) {
                float v = EXP2(acc0[reg]);
                tot_a[0][reg] += v;
                if (rowlab[0][reg] == lc) pos_a[0][reg] += v;
            }
        }
        if (ct == rt0 + 1) {                  // wave-uniform: diag tile, tr=1
            #pragma unroll
            for (int reg = 0; reg < 4; ++reg) {
                float v = EXP2(acc1[reg]);
                if ((q * 4 + reg) == c) v = 0.f;
                tot_a[1][reg] += v;
                if (rowlab[1][reg] == lc) pos_a[1][reg] += v;
            }
        } else {
            #pragma unroll
            for (int reg = 0; reg < 4; ++reg) {
                float v = EXP2(acc1[reg]);
                tot_a[1][reg] += v;
                if (rowlab[1][reg] == lc) pos_a[1][reg] += v;
            }
        }
    }

    // ---- reduce over the 16 column-lanes, one atomic per row ----
    #pragma unroll
    for (int tr = 0; tr < 2; ++tr)
        #pragma unroll
        for (int reg = 0; reg < 4; ++reg) {
            float t = tot_a[tr][reg];
            float p = pos_a[tr][reg];
            #pragma unroll
            for (int m = 1; m < 16; m <<= 1) {
                t += __shfl_xor(t, m, 64);
                p += __shfl_xor(p, m, 64);
            }
            if (c == 0) {
                const int r = w0 + tr * 16 + q * 4 + reg;
                atomicAdd(&tot[r], t);   // device-scope RMW at coherent point
                atomicAdd(&pos[r], p);
            }
        }

    // ---- last-block finalize: completion-wait + relaxed ticket (NO cache ops)
    asm volatile("s_waitcnt vmcnt(0)" ::: "memory");  // our atomics committed
    __syncthreads();
    if (tid == 0)
        s_ticket = __hip_atomic_fetch_add(ticket, 1, __ATOMIC_RELAXED,
                                          __HIP_MEMORY_SCOPE_AGENT);
    __syncthreads();
    if (s_ticket != NBLK - 1) return;

    float lsum = 0.f, lcnt = 0.f;
    #pragma unroll 4
    for (int i = tid; i < N; i += 256) {
        const float t = __hip_atomic_load(&tot[i], __ATOMIC_RELAXED,
                                          __HIP_MEMORY_SCOPE_AGENT);
        const float p = __hip_atomic_load(&pos[i], __ATOMIC_RELAXED,
                                          __HIP_MEMORY_SCOPE_AGENT);
        const float loss = -__logf(p / (t + 1e-8f) + 1e-8f);
        if (p > 0.f) { lsum += loss; lcnt += 1.f; }   // valid <=> pos>0
    }
    #pragma unroll
    for (int m = 1; m < 64; m <<= 1) {
        lsum += __shfl_xor(lsum, m, 64);
        lcnt += __shfl_xor(lcnt, m, 64);
    }
    if (lane == 0) { sred[0][wave] = lsum; sred[1][wave] = lcnt; }
    __syncthreads();
    if (tid == 0) {
        const float s = sred[0][0] + sred[0][1] + sred[0][2] + sred[0][3];
        const float n = sred[1][0] + sred[1][1] + sred[1][2] + sred[1][3];
        out[0] = (n > 0.f) ? s / fmaxf(n, 1.f) : 0.f;
    }
}

extern "C" void kernel_launch(void* const* d_in, const int* in_sizes, int n_in,
                              void* d_out, int out_size, void* d_ws, size_t ws_size,
                              hipStream_t stream) {
    const float* emb  = (const float*)d_in[0];
    const int* labels = (const int*)d_in[1];
    unsigned short* bfA = (unsigned short*)d_ws;                       // 2 MB, frag-major, scaled
    unsigned short* bfB = bfA + (size_t)N * D;                         // 2 MB, frag-major
    float* tot    = (float*)(bfB + (size_t)N * D);
    float* pos    = tot + N;
    int*   ticket = (int*)(pos + N);

    cl_prep<<<NBLK_PREP, 256, 0, stream>>>(emb, bfA, bfB, tot, ticket);
    cl_main<<<NBLK, 256, 0, stream>>>(bfA, bfB, labels, tot, pos,
                                      ticket, (float*)d_out);
}